// Round 4
// baseline (1111.219 us; speedup 1.0000x reference)
//
#include <hip/hip_runtime.h>

#define NUM_GRAPHS 1024
#define BIN_BITS 10
#define BIN_SIZE (1 << BIN_BITS)      // 1024 nodes per bin
#define EB 4096                       // edges per binning block
#define STH 512                       // scatter threads (8 waves)
#define EPT 8                         // edges per thread in scatter (EB/STH)
#define SWAVES 8                      // scatter waves per block
#define CURS 16                       // cursor stride in ints (64 B = 1 line)
#define ACCTH 256                     // accum threads (4 waves)
#define ACCW 4                        // waves per accum block

typedef int v4i __attribute__((ext_vector_type(4)));  // native vec for nt-load

// ---------------------------------------------------------------------------
// Prep: line-padded cursors to bin bases, zero pool accumulators, x -> packed
// bf16x4 (8 B/node, 3.8 MB: fits XCD L2 -> accum gather is cache-resident).
// ---------------------------------------------------------------------------
__device__ inline unsigned bf16_rn(float f) {
    unsigned u = __float_as_uint(f);
    return (u + 0x7FFFu + ((u >> 16) & 1u)) >> 16;
}
__global__ void prep_kernel(const float4* __restrict__ x, uint2* __restrict__ x16,
                            int N, int* __restrict__ cursor,
                            float* __restrict__ gsum, float* __restrict__ gcnt,
                            int cap) {
    int i = blockIdx.x * blockDim.x + threadIdx.x;
    if (i < 512) cursor[i * CURS] = i * cap;   // one cache line per bin cursor
    if (i < NUM_GRAPHS * 4) gsum[i] = 0.0f;
    if (i < NUM_GRAPHS) gcnt[i] = 0.0f;
    if (i < N) {
        float4 v = x[i];
        uint2 r;
        r.x = bf16_rn(v.x) | (bf16_rn(v.y) << 16);
        r.y = bf16_rn(v.z) | (bf16_rn(v.w) << 16);
        x16[i] = r;
    }
}

// ---------------------------------------------------------------------------
// bin_scatter v7: ZERO per-edge atomics. v6's 16M LDS rtn atomics cost
// ~3.8 cy/lane-op (~243 cy/wave-instr vs ~6 for plain ds ops) = ~99 us floor.
// Replaced by the same ballot-match + plain-RMW trick accum v7 uses:
//  - per-WAVE private hist[8][512] (no cross-wave races);
//  - per 64-edge round: 9-bit ballot match on bn -> group mask, cnt, rank,
//    leader; ALL lanes plain-read hist[wave][bn] (group lanes broadcast);
//    leader alone writes old+cnt. lp = old + rank. Same-wave LDS program
//    order makes round k's write visible to round k+1's read.
//  - combine: thread t sums 8 wave-counts of bin t, reserves cursor space
//    once (line-padded), writes wbase[w][t] = base + prefix_w.
//  - pass B: pos = wbase[wave][bn] + lp, direct nt store.
// LDS 32 KB, no atomic serial path; launch_bounds(512,6) -> ~24 waves/CU.
// packed = (dst_local << 19) | src.
// ---------------------------------------------------------------------------
__global__ void __launch_bounds__(STH, 6) bin_scatter(const int* __restrict__ src,
                                                      const int* __restrict__ dst,
                                                      int* __restrict__ packed,
                                                      int* __restrict__ cursor,
                                                      int E, int cap, int nb) {
    __shared__ int hist[SWAVES][512];     // per-wave counts (plain RMW)
    __shared__ int wbase[SWAVES][512];    // per-wave global write base per bin

    const int t = threadIdx.x;
    const int lane = t & 63;
    const int wave = t >> 6;
    const int b0 = blockIdx.x * EB;
    const int myBase = b0 + t * EPT;

    for (int j = t; j < SWAVES * 512; j += STH) (&hist[0][0])[j] = 0;
    __syncthreads();

    // ---- load 8 edges per thread (two int4 each of src/dst) ----
    int dbuf[EPT], sbuf[EPT];
    const bool full = (myBase + EPT <= E);
    if (full) {
        *(int4*)(dbuf)     = *(const int4*)(dst + myBase);
        *(int4*)(dbuf + 4) = *(const int4*)(dst + myBase + 4);
        *(int4*)(sbuf)     = *(const int4*)(src + myBase);
        *(int4*)(sbuf + 4) = *(const int4*)(src + myBase + 4);
    } else {
#pragma unroll
        for (int i = 0; i < EPT; ++i) {
            int e = myBase + i;
            bool ok = e < E;
            dbuf[i] = ok ? dst[e] : 0;
            sbuf[i] = ok ? src[e] : 0;
        }
    }

    // ---- pass A: ballot-match ranking, plain LDS RMW (no atomics) ----
    int pv[EPT];                   // packed edge values
    int bnlp[EPT];                 // (bn << 16) | lp, or -1 if invalid
#pragma unroll
    for (int k = 0; k < EPT; ++k) {
        int e = myBase + k;
        bool ok = full || (e < E);
        int d = dbuf[k];
        int bn = ((unsigned)d) >> BIN_BITS;            // < 512
        pv[k] = ((d & (BIN_SIZE - 1)) << 19) | sbuf[k];
        unsigned long long m = __ballot(ok);
#pragma unroll
        for (int bb = 0; bb < 9; ++bb) {
            unsigned long long bm = __ballot((bn >> bb) & 1);
            m &= ((bn >> bb) & 1) ? bm : ~bm;
        }
        int rank = (int)__popcll(m & ((1ull << lane) - 1ull));
        int cnt  = (int)__popcll(m);
        int leader = __ffsll((unsigned long long)m) - 1;
        int old = hist[wave][bn];                      // group lanes: same addr
        if (ok && lane == leader) hist[wave][bn] = old + cnt;
        bnlp[k] = ok ? ((bn << 16) | (old + rank)) : -1;
    }
    __syncthreads();

    // ---- combine: per-bin cross-wave prefix + single cursor reserve ----
    {
        int c[SWAVES];
        int total = 0;
#pragma unroll
        for (int w = 0; w < SWAVES; ++w) { c[w] = hist[w][t]; total += c[w]; }
        int base = 0;
        if (t < nb && total > 0) base = atomicAdd(&cursor[t * CURS], total);
        int acc = base;
#pragma unroll
        for (int w = 0; w < SWAVES; ++w) { wbase[w][t] = acc; acc += c[w]; }
    }
    __syncthreads();

    // ---- pass B: direct scattered stores: pos = wbase[wave][bn] + lp ----
    if (full) {
#pragma unroll
        for (int k = 0; k < EPT; ++k) {
            int bn = ((unsigned)bnlp[k]) >> 16;
            int lp = bnlp[k] & 0xFFFF;
            int pos = wbase[wave][bn] + lp;
            if (pos < (bn + 1) * cap)          // overflow guard (~28 sigma)
                __builtin_nontemporal_store(pv[k], &packed[pos]);
        }
    } else {
#pragma unroll
        for (int k = 0; k < EPT; ++k) {
            if (bnlp[k] >= 0) {
                int bn = ((unsigned)bnlp[k]) >> 16;
                int lp = bnlp[k] & 0xFFFF;
                int pos = wbase[wave][bn] + lp;
                if (pos < (bn + 1) * cap)
                    __builtin_nontemporal_store(pv[k], &packed[pos]);
            }
        }
    }
}

// ---------------------------------------------------------------------------
// Accum v7 (UNCHANGED — control for attribution): zero-atomic scatter-add.
// Per-wave private planes [4][1024][4] f32 = 64 KB; intra-wave same-dl
// collisions resolved in registers via 11-ballot match + rank-ordered RMW.
// ---------------------------------------------------------------------------
__global__ void __launch_bounds__(ACCTH) bin_accum_mlp_pool(
        const float4* __restrict__ x,
        const uint2* __restrict__ x16,
        const int* __restrict__ packed,
        const int* __restrict__ cursor,
        const int* __restrict__ batch,
        const float* __restrict__ eps_p,
        const float* __restrict__ W1, const float* __restrict__ b1,
        const float* __restrict__ W2, const float* __restrict__ b2,
        float* __restrict__ gsum, float* __restrict__ gcnt,
        int N, int cap) {
    __shared__ float planes[ACCW][BIN_SIZE][4];   // 64 KB, per-wave private

    const int bin = blockIdx.x;
    const int t = threadIdx.x;
    const int lane = t & 63;
    const int wave = t >> 6;

    // zero planes: 4096 float4s / 256 threads = 16 each
    {
        float4* pz = (float4*)&planes[0][0][0];
        float4 z; z.x = 0.f; z.y = 0.f; z.z = 0.f; z.w = 0.f;
#pragma unroll
        for (int i = 0; i < 16; ++i) pz[t + i * ACCTH] = z;
    }
    __syncthreads();

    const int start = bin * cap;
    int end = cursor[bin * CURS];
    if (end > start + cap) end = start + cap;
    int cnt = end - start; if (cnt < 0) cnt = 0;

    // contiguous per-wave segments, 16B-aligned bases
    int seg = ((cnt + ACCW - 1) / ACCW + 3) & ~3;
    int s0 = start + wave * seg;
    int s1 = s0 + seg; if (s1 > end) s1 = end;

    // one edge per lane per round; 4 rounds per 16B packed load
    for (int base = s0; base < s1; base += 256) {
        int b = base + lane * 4;
        int pe[4];
        if (b + 3 < s1) {
            v4i p4 = __builtin_nontemporal_load((const v4i*)(packed + b));
            pe[0] = p4.x; pe[1] = p4.y; pe[2] = p4.z; pe[3] = p4.w;
        } else {
            pe[0] = (b + 0 < s1) ? packed[b + 0] : -1;
            pe[1] = (b + 1 < s1) ? packed[b + 1] : -1;
            pe[2] = (b + 2 < s1) ? packed[b + 2] : -1;
            pe[3] = (b + 3 < s1) ? packed[b + 3] : -1;
        }
        // issue all 4 gathers up-front (L2-resident x16); invalid -> masked
        // index 0x7FFFF still lands inside ws (packed region), value unused.
        uint2 g[4];
#pragma unroll
        for (int k = 0; k < 4; ++k) g[k] = x16[pe[k] & 0x7FFFF];

#pragma unroll
        for (int k = 0; k < 4; ++k) {
            int p = pe[k];
            bool ok = p >= 0;
            int dl = (((unsigned)p) >> 19) & (BIN_SIZE - 1);
            // ---- 11-ballot match: lanes sharing my dl (valid lanes only) --
            unsigned long long m;
            {
                unsigned long long bv = __ballot(ok);
                m = ok ? bv : ~bv;
#pragma unroll
                for (int bb = 0; bb < BIN_BITS; ++bb) {
                    unsigned long long bl_ = __ballot((dl >> bb) & 1);
                    m &= ((dl >> bb) & 1) ? bl_ : ~bl_;
                }
            }
            int rank = ok ? (int)__popcll(m & ((1ull << lane) - 1ull)) : -1;

            float v0 = __uint_as_float(g[k].x << 16);
            float v1 = __uint_as_float(g[k].x & 0xFFFF0000u);
            float v2 = __uint_as_float(g[k].y << 16);
            float v3 = __uint_as_float(g[k].y & 0xFFFF0000u);
            float4* pp = (float4*)&planes[wave][dl][0];
            // rank-ordered RMW passes; singleton groups -> exactly 1 pass
            for (int pass = 0; __any(rank >= pass); ++pass) {
                if (rank == pass) {
                    float4 a = *pp;
                    a.x += v0; a.y += v1; a.z += v2; a.w += v3;
                    *pp = a;
                }
            }
        }
    }
    __syncthreads();

    // ---- reduce 4 planes + MLP + pool; 4 node-batches of 256 ----
    const float eps = eps_p[0];
    for (int half = 0; half < 4; ++half) {
        int node = t + half * ACCTH;           // 0..1023
        float4 a = *(const float4*)&planes[0][node][0];
#pragma unroll
        for (int w = 1; w < ACCW; ++w) {
            float4 bq = *(const float4*)&planes[w][node][0];
            a.x += bq.x; a.y += bq.y; a.z += bq.z; a.w += bq.w;
        }

        int n = bin * BIN_SIZE + node;         // one node per thread
        bool valid = n < N;
        float o0 = 0.f, o1 = 0.f, o2 = 0.f, o3 = 0.f;
        int g = -1;
        if (valid) {
            float4 xv = x[n];
            float h0 = (1.0f + eps) * xv.x + a.x;
            float h1 = (1.0f + eps) * xv.y + a.y;
            float h2 = (1.0f + eps) * xv.z + a.z;
            float h3 = (1.0f + eps) * xv.w + a.w;

            float tmp[16];
#pragma unroll
            for (int j = 0; j < 16; ++j) {
                float v = b1[j] + h0 * W1[j] + h1 * W1[16 + j] + h2 * W1[32 + j] + h3 * W1[48 + j];
                tmp[j] = v > 0.0f ? v : 0.0f;
            }
            float o[4];
#pragma unroll
            for (int j = 0; j < 4; ++j) {
                float v = b2[j];
#pragma unroll
                for (int k = 0; k < 16; ++k) v += tmp[k] * W2[k * 4 + j];
                o[j] = v > 0.0f ? v : 0.0f;
            }
            o0 = o[0]; o1 = o[1]; o2 = o[2]; o3 = o[3];
            g = batch[n];
        }

        // batch is sorted -> waves almost always graph-uniform
        int g0 = __shfl(g, 0);
        bool uni = __all(g == g0);
        if (uni && g0 >= 0) {
#pragma unroll
            for (int off = 32; off > 0; off >>= 1) {
                o0 += __shfl_down(o0, off);
                o1 += __shfl_down(o1, off);
                o2 += __shfl_down(o2, off);
                o3 += __shfl_down(o3, off);
            }
            if (lane == 0) {
                unsafeAtomicAdd(&gsum[(size_t)g0 * 4 + 0], o0);
                unsafeAtomicAdd(&gsum[(size_t)g0 * 4 + 1], o1);
                unsafeAtomicAdd(&gsum[(size_t)g0 * 4 + 2], o2);
                unsafeAtomicAdd(&gsum[(size_t)g0 * 4 + 3], o3);
                unsafeAtomicAdd(&gcnt[g0], 64.0f);
            }
        } else if (valid) {
            unsafeAtomicAdd(&gsum[(size_t)g * 4 + 0], o0);
            unsafeAtomicAdd(&gsum[(size_t)g * 4 + 1], o1);
            unsafeAtomicAdd(&gsum[(size_t)g * 4 + 2], o2);
            unsafeAtomicAdd(&gsum[(size_t)g * 4 + 3], o3);
            unsafeAtomicAdd(&gcnt[g], 1.0f);
        }
    }
}

// ---------------------------------------------------------------------------
// pooled = sums / max(cnt,1); out = log_softmax per graph.
// ---------------------------------------------------------------------------
__global__ void pool_softmax_kernel(const float* __restrict__ gsum,
                                    const float* __restrict__ gcnt,
                                    float* __restrict__ out) {
    int g = blockIdx.x * blockDim.x + threadIdx.x;
    if (g >= NUM_GRAPHS) return;
    float c = fmaxf(gcnt[g], 1.0f);
    float p0 = gsum[g * 4 + 0] / c;
    float p1 = gsum[g * 4 + 1] / c;
    float p2 = gsum[g * 4 + 2] / c;
    float p3 = gsum[g * 4 + 3] / c;
    float m = fmaxf(fmaxf(p0, p1), fmaxf(p2, p3));
    float s = expf(p0 - m) + expf(p1 - m) + expf(p2 - m) + expf(p3 - m);
    float lse = m + logf(s);
    out[g * 4 + 0] = p0 - lse;
    out[g * 4 + 1] = p1 - lse;
    out[g * 4 + 2] = p2 - lse;
    out[g * 4 + 3] = p3 - lse;
}

// ---------------------------------------------------------------------------
// Fallback kernels (ws too small): direct atomic scatter + separate MLP/pool.
// ---------------------------------------------------------------------------
__global__ void edge_scatter_kernel(const float4* __restrict__ x,
                                    const int* __restrict__ src,
                                    const int* __restrict__ dst,
                                    float* __restrict__ agg,
                                    int E) {
    int t = blockIdx.x * blockDim.x + threadIdx.x;
    int e = t * 4;
    if (e + 3 < E) {
        int4 s = *(const int4*)(src + e);
        int4 d = *(const int4*)(dst + e);
        float4 xv;
        xv = x[s.x];
        unsafeAtomicAdd(&agg[(size_t)d.x * 4 + 0], xv.x);
        unsafeAtomicAdd(&agg[(size_t)d.x * 4 + 1], xv.y);
        unsafeAtomicAdd(&agg[(size_t)d.x * 4 + 2], xv.z);
        unsafeAtomicAdd(&agg[(size_t)d.x * 4 + 3], xv.w);
        xv = x[s.y];
        unsafeAtomicAdd(&agg[(size_t)d.y * 4 + 0], xv.x);
        unsafeAtomicAdd(&agg[(size_t)d.y * 4 + 1], xv.y);
        unsafeAtomicAdd(&agg[(size_t)d.y * 4 + 2], xv.z);
        unsafeAtomicAdd(&agg[(size_t)d.y * 4 + 3], xv.w);
        xv = x[s.z];
        unsafeAtomicAdd(&agg[(size_t)d.z * 4 + 0], xv.x);
        unsafeAtomicAdd(&agg[(size_t)d.z * 4 + 1], xv.y);
        unsafeAtomicAdd(&agg[(size_t)d.z * 4 + 2], xv.z);
        unsafeAtomicAdd(&agg[(size_t)d.z * 4 + 3], xv.w);
        xv = x[s.w];
        unsafeAtomicAdd(&agg[(size_t)d.w * 4 + 0], xv.x);
        unsafeAtomicAdd(&agg[(size_t)d.w * 4 + 1], xv.y);
        unsafeAtomicAdd(&agg[(size_t)d.w * 4 + 2], xv.z);
        unsafeAtomicAdd(&agg[(size_t)d.w * 4 + 3], xv.w);
    } else {
        for (int i = e; i < E; ++i) {
            int sv = src[i], dv = dst[i];
            float4 xv = x[sv];
            unsafeAtomicAdd(&agg[(size_t)dv * 4 + 0], xv.x);
            unsafeAtomicAdd(&agg[(size_t)dv * 4 + 1], xv.y);
            unsafeAtomicAdd(&agg[(size_t)dv * 4 + 2], xv.z);
            unsafeAtomicAdd(&agg[(size_t)dv * 4 + 3], xv.w);
        }
    }
}

__global__ void node_mlp_pool_kernel(const float4* __restrict__ x,
                                     const float4* __restrict__ agg,
                                     const int* __restrict__ batch,
                                     const float* __restrict__ eps_p,
                                     const float* __restrict__ W1,
                                     const float* __restrict__ b1,
                                     const float* __restrict__ W2,
                                     const float* __restrict__ b2,
                                     float* __restrict__ gsum,
                                     float* __restrict__ gcnt,
                                     int N) {
    int i = blockIdx.x * blockDim.x + threadIdx.x;
    bool valid = i < N;
    float o0 = 0.f, o1 = 0.f, o2 = 0.f, o3 = 0.f;
    int g = -1;
    if (valid) {
        float eps = eps_p[0];
        float4 xv = x[i];
        float4 av = agg[i];
        float h0 = (1.0f + eps) * xv.x + av.x;
        float h1 = (1.0f + eps) * xv.y + av.y;
        float h2 = (1.0f + eps) * xv.z + av.z;
        float h3 = (1.0f + eps) * xv.w + av.w;
        float tmp[16];
#pragma unroll
        for (int j = 0; j < 16; ++j) {
            float v = b1[j] + h0 * W1[j] + h1 * W1[16 + j] + h2 * W1[32 + j] + h3 * W1[48 + j];
            tmp[j] = v > 0.0f ? v : 0.0f;
        }
        float o[4];
#pragma unroll
        for (int j = 0; j < 4; ++j) {
            float v = b2[j];
#pragma unroll
            for (int k = 0; k < 16; ++k) v += tmp[k] * W2[k * 4 + j];
            o[j] = v > 0.0f ? v : 0.0f;
        }
        o0 = o[0]; o1 = o[1]; o2 = o[2]; o3 = o[3];
        g = batch[i];
    }
    int g0 = __shfl(g, 0);
    bool uni = __all(g == g0);
    if (uni && g0 >= 0) {
#pragma unroll
        for (int off = 32; off > 0; off >>= 1) {
            o0 += __shfl_down(o0, off);
            o1 += __shfl_down(o1, off);
            o2 += __shfl_down(o2, off);
            o3 += __shfl_down(o3, off);
        }
        if ((threadIdx.x & 63) == 0) {
            unsafeAtomicAdd(&gsum[(size_t)g0 * 4 + 0], o0);
            unsafeAtomicAdd(&gsum[(size_t)g0 * 4 + 1], o1);
            unsafeAtomicAdd(&gsum[(size_t)g0 * 4 + 2], o2);
            unsafeAtomicAdd(&gsum[(size_t)g0 * 4 + 3], o3);
            unsafeAtomicAdd(&gcnt[g0], 64.0f);
        }
    } else if (valid) {
        unsafeAtomicAdd(&gsum[(size_t)g * 4 + 0], o0);
        unsafeAtomicAdd(&gsum[(size_t)g * 4 + 1], o1);
        unsafeAtomicAdd(&gsum[(size_t)g * 4 + 2], o2);
        unsafeAtomicAdd(&gsum[(size_t)g * 4 + 3], o3);
        unsafeAtomicAdd(&gcnt[g], 1.0f);
    }
}

extern "C" void kernel_launch(void* const* d_in, const int* in_sizes, int n_in,
                              void* d_out, int out_size, void* d_ws, size_t ws_size,
                              hipStream_t stream) {
    const float* x     = (const float*)d_in[0];
    const int*   ei    = (const int*)d_in[1];
    const int*   batch = (const int*)d_in[2];
    const float* eps   = (const float*)d_in[3];
    const float* W1    = (const float*)d_in[4];
    const float* b1    = (const float*)d_in[5];
    const float* W2    = (const float*)d_in[6];
    const float* b2    = (const float*)d_in[7];

    const int N = in_sizes[0] / 4;
    const int E = in_sizes[1] / 2;
    const int* src = ei;
    const int* dst = ei + (size_t)E;

    const int nb = (N + BIN_SIZE - 1) >> BIN_BITS;   // 489 for N=500K
    const int epb = (E + nb - 1) / nb;
    int cap = epb + epb / 8 + 1024;                  // ~28 sigma headroom
    cap = (cap + 3) & ~3;                            // 16B-align chunk bases

    // Fast-path ws layout: x16 [2N] | packed [nb*cap] | cursor [512*CURS] |
    //                      gsum [G*4] | gcnt [G]      (4 B units)
    size_t x16_elems = ((size_t)2 * N + 3) & ~(size_t)3;
    size_t packed_elems = ((size_t)nb * cap + 3) & ~(size_t)3;
    size_t need = (x16_elems + packed_elems + 512 * CURS + NUM_GRAPHS * 5) * sizeof(float);

    if (nb <= 512 && N < (1 << 19) && need <= ws_size) {
        uint2* x16    = (uint2*)d_ws;
        int*   packed = (int*)d_ws + x16_elems;
        int*   cursor = packed + packed_elems;
        float* gsum   = (float*)(cursor + 512 * CURS);
        float* gcnt   = gsum + (size_t)NUM_GRAPHS * 4;

        prep_kernel<<<(N + 511) / 512, 512, 0, stream>>>(
            (const float4*)x, x16, N, cursor, gsum, gcnt, cap);

        int nblocks_e = (E + EB - 1) / EB;
        bin_scatter<<<nblocks_e, STH, 0, stream>>>(src, dst, packed, cursor, E, cap, nb);

        bin_accum_mlp_pool<<<nb, ACCTH, 0, stream>>>(
            (const float4*)x, (const uint2*)x16, packed, cursor, batch, eps,
            W1, b1, W2, b2, gsum, gcnt, N, cap);

        pool_softmax_kernel<<<(NUM_GRAPHS + 255) / 256, 256, 0, stream>>>(
            gsum, gcnt, (float*)d_out);
    } else {
        float* agg  = (float*)d_ws;
        float* gsum = agg + (size_t)N * 4;
        float* gcnt = gsum + (size_t)NUM_GRAPHS * 4;
        size_t zero_bytes = ((size_t)N * 4 + NUM_GRAPHS * 5) * sizeof(float);
        (void)hipMemsetAsync(d_ws, 0, zero_bytes, stream);

        int e4 = (E + 3) / 4;
        edge_scatter_kernel<<<(e4 + 255) / 256, 256, 0, stream>>>(
            (const float4*)x, src, dst, agg, E);

        node_mlp_pool_kernel<<<(N + 255) / 256, 256, 0, stream>>>(
            (const float4*)x, (const float4*)agg, batch, eps, W1, b1, W2, b2,
            gsum, gcnt, N);

        pool_softmax_kernel<<<(NUM_GRAPHS + 255) / 256, 256, 0, stream>>>(
            gsum, gcnt, (float*)d_out);
    }
}

// Round 5
// 429.709 us; speedup vs baseline: 2.5860x; 2.5860x over previous
//
#include <hip/hip_runtime.h>

#define NUM_GRAPHS 1024
#define BIN_BITS 10
#define BIN_SIZE (1 << BIN_BITS)      // 1024 nodes per bin
#define EB 4096                       // edges per binning block
#define STH 512                       // scatter threads (8 waves)
#define EPT 8                         // edges per thread in scatter (EB/STH)
#define SWAVES 8                      // scatter waves per block
#define CURS 16                       // cursor stride in ints (64 B = 1 line)
#define ACCTH 256                     // accum threads (4 waves)
#define ACCW 4                        // waves per accum block

typedef int v4i __attribute__((ext_vector_type(4)));  // native vec for nt-load

// ---------------------------------------------------------------------------
// Prep: line-padded cursors to bin bases, zero pool accumulators, x -> packed
// bf16x4 (8 B/node, 3.8 MB: fits XCD L2 -> accum gather is cache-resident).
// ---------------------------------------------------------------------------
__device__ inline unsigned bf16_rn(float f) {
    unsigned u = __float_as_uint(f);
    return (u + 0x7FFFu + ((u >> 16) & 1u)) >> 16;
}
__global__ void prep_kernel(const float4* __restrict__ x, uint2* __restrict__ x16,
                            int N, int* __restrict__ cursor,
                            float* __restrict__ gsum, float* __restrict__ gcnt,
                            int cap) {
    int i = blockIdx.x * blockDim.x + threadIdx.x;
    if (i < 512) cursor[i * CURS] = i * cap;   // one cache line per bin cursor
    if (i < NUM_GRAPHS * 4) gsum[i] = 0.0f;
    if (i < NUM_GRAPHS) gcnt[i] = 0.0f;
    if (i < N) {
        float4 v = x[i];
        uint2 r;
        r.x = bf16_rn(v.x) | (bf16_rn(v.y) << 16);
        r.y = bf16_rn(v.z) | (bf16_rn(v.w) << 16);
        x16[i] = r;
    }
}

// ---------------------------------------------------------------------------
// bin_scatter v8 = v7 with the ONE fix: scattered stores go through L2
// (plain stores), NOT nontemporal. r4 post-mortem: nt on scattered 4B
// stores bypassed L2 -> 16M partial-line HBM writes (~660 MB, 815 us).
// L2 merges neighboring blocks' writes to the same bin into full lines.
// Zero per-edge atomics (ballot-match ranking, per-wave hist) retained.
// packed = (dst_local << 19) | src.
// ---------------------------------------------------------------------------
__global__ void __launch_bounds__(STH, 6) bin_scatter(const int* __restrict__ src,
                                                      const int* __restrict__ dst,
                                                      int* __restrict__ packed,
                                                      int* __restrict__ cursor,
                                                      int E, int cap, int nb) {
    __shared__ int hist[SWAVES][512];     // per-wave counts (plain RMW)
    __shared__ int wbase[SWAVES][512];    // per-wave global write base per bin

    const int t = threadIdx.x;
    const int lane = t & 63;
    const int wave = t >> 6;
    const int b0 = blockIdx.x * EB;
    const int myBase = b0 + t * EPT;

    for (int j = t; j < SWAVES * 512; j += STH) (&hist[0][0])[j] = 0;
    __syncthreads();

    // ---- load 8 edges per thread (two int4 each of src/dst) ----
    int dbuf[EPT], sbuf[EPT];
    const bool full = (myBase + EPT <= E);
    if (full) {
        *(int4*)(dbuf)     = *(const int4*)(dst + myBase);
        *(int4*)(dbuf + 4) = *(const int4*)(dst + myBase + 4);
        *(int4*)(sbuf)     = *(const int4*)(src + myBase);
        *(int4*)(sbuf + 4) = *(const int4*)(src + myBase + 4);
    } else {
#pragma unroll
        for (int i = 0; i < EPT; ++i) {
            int e = myBase + i;
            bool ok = e < E;
            dbuf[i] = ok ? dst[e] : 0;
            sbuf[i] = ok ? src[e] : 0;
        }
    }

    // ---- pass A: ballot-match ranking, plain LDS RMW (no atomics) ----
    int pv[EPT];                   // packed edge values
    int bnlp[EPT];                 // (bn << 16) | lp, or -1 if invalid
#pragma unroll
    for (int k = 0; k < EPT; ++k) {
        int e = myBase + k;
        bool ok = full || (e < E);
        int d = dbuf[k];
        int bn = ((unsigned)d) >> BIN_BITS;            // < 512
        pv[k] = ((d & (BIN_SIZE - 1)) << 19) | sbuf[k];
        unsigned long long m = __ballot(ok);
#pragma unroll
        for (int bb = 0; bb < 9; ++bb) {
            unsigned long long bm = __ballot((bn >> bb) & 1);
            m &= ((bn >> bb) & 1) ? bm : ~bm;
        }
        int rank = (int)__popcll(m & ((1ull << lane) - 1ull));
        int cnt  = (int)__popcll(m);
        int leader = __ffsll((unsigned long long)m) - 1;
        int old = hist[wave][bn];                      // group lanes: same addr
        if (ok && lane == leader) hist[wave][bn] = old + cnt;
        bnlp[k] = ok ? ((bn << 16) | (old + rank)) : -1;
    }
    __syncthreads();

    // ---- combine: per-bin cross-wave prefix + single cursor reserve ----
    {
        int c[SWAVES];
        int total = 0;
#pragma unroll
        for (int w = 0; w < SWAVES; ++w) { c[w] = hist[w][t]; total += c[w]; }
        int base = 0;
        if (t < nb && total > 0) base = atomicAdd(&cursor[t * CURS], total);
        int acc = base;
#pragma unroll
        for (int w = 0; w < SWAVES; ++w) { wbase[w][t] = acc; acc += c[w]; }
    }
    __syncthreads();

    // ---- pass B: direct scattered stores THROUGH L2 (plain, not nt) ----
    if (full) {
#pragma unroll
        for (int k = 0; k < EPT; ++k) {
            int bn = ((unsigned)bnlp[k]) >> 16;
            int lp = bnlp[k] & 0xFFFF;
            int pos = wbase[wave][bn] + lp;
            if (pos < (bn + 1) * cap)          // overflow guard (~28 sigma)
                packed[pos] = pv[k];
        }
    } else {
#pragma unroll
        for (int k = 0; k < EPT; ++k) {
            if (bnlp[k] >= 0) {
                int bn = ((unsigned)bnlp[k]) >> 16;
                int lp = bnlp[k] & 0xFFFF;
                int pos = wbase[wave][bn] + lp;
                if (pos < (bn + 1) * cap)
                    packed[pos] = pv[k];
            }
        }
    }
}

// ---------------------------------------------------------------------------
// Accum v7 (UNCHANGED — control for attribution): zero-atomic scatter-add.
// Per-wave private planes [4][1024][4] f32 = 64 KB; intra-wave same-dl
// collisions resolved in registers via 11-ballot match + rank-ordered RMW.
// ---------------------------------------------------------------------------
__global__ void __launch_bounds__(ACCTH) bin_accum_mlp_pool(
        const float4* __restrict__ x,
        const uint2* __restrict__ x16,
        const int* __restrict__ packed,
        const int* __restrict__ cursor,
        const int* __restrict__ batch,
        const float* __restrict__ eps_p,
        const float* __restrict__ W1, const float* __restrict__ b1,
        const float* __restrict__ W2, const float* __restrict__ b2,
        float* __restrict__ gsum, float* __restrict__ gcnt,
        int N, int cap) {
    __shared__ float planes[ACCW][BIN_SIZE][4];   // 64 KB, per-wave private

    const int bin = blockIdx.x;
    const int t = threadIdx.x;
    const int lane = t & 63;
    const int wave = t >> 6;

    // zero planes: 4096 float4s / 256 threads = 16 each
    {
        float4* pz = (float4*)&planes[0][0][0];
        float4 z; z.x = 0.f; z.y = 0.f; z.z = 0.f; z.w = 0.f;
#pragma unroll
        for (int i = 0; i < 16; ++i) pz[t + i * ACCTH] = z;
    }
    __syncthreads();

    const int start = bin * cap;
    int end = cursor[bin * CURS];
    if (end > start + cap) end = start + cap;
    int cnt = end - start; if (cnt < 0) cnt = 0;

    // contiguous per-wave segments, 16B-aligned bases
    int seg = ((cnt + ACCW - 1) / ACCW + 3) & ~3;
    int s0 = start + wave * seg;
    int s1 = s0 + seg; if (s1 > end) s1 = end;

    // one edge per lane per round; 4 rounds per 16B packed load
    for (int base = s0; base < s1; base += 256) {
        int b = base + lane * 4;
        int pe[4];
        if (b + 3 < s1) {
            v4i p4 = __builtin_nontemporal_load((const v4i*)(packed + b));
            pe[0] = p4.x; pe[1] = p4.y; pe[2] = p4.z; pe[3] = p4.w;
        } else {
            pe[0] = (b + 0 < s1) ? packed[b + 0] : -1;
            pe[1] = (b + 1 < s1) ? packed[b + 1] : -1;
            pe[2] = (b + 2 < s1) ? packed[b + 2] : -1;
            pe[3] = (b + 3 < s1) ? packed[b + 3] : -1;
        }
        // issue all 4 gathers up-front (L2-resident x16); invalid -> masked
        // index 0x7FFFF still lands inside ws (packed region), value unused.
        uint2 g[4];
#pragma unroll
        for (int k = 0; k < 4; ++k) g[k] = x16[pe[k] & 0x7FFFF];

#pragma unroll
        for (int k = 0; k < 4; ++k) {
            int p = pe[k];
            bool ok = p >= 0;
            int dl = (((unsigned)p) >> 19) & (BIN_SIZE - 1);
            // ---- 11-ballot match: lanes sharing my dl (valid lanes only) --
            unsigned long long m;
            {
                unsigned long long bv = __ballot(ok);
                m = ok ? bv : ~bv;
#pragma unroll
                for (int bb = 0; bb < BIN_BITS; ++bb) {
                    unsigned long long bl_ = __ballot((dl >> bb) & 1);
                    m &= ((dl >> bb) & 1) ? bl_ : ~bl_;
                }
            }
            int rank = ok ? (int)__popcll(m & ((1ull << lane) - 1ull)) : -1;

            float v0 = __uint_as_float(g[k].x << 16);
            float v1 = __uint_as_float(g[k].x & 0xFFFF0000u);
            float v2 = __uint_as_float(g[k].y << 16);
            float v3 = __uint_as_float(g[k].y & 0xFFFF0000u);
            float4* pp = (float4*)&planes[wave][dl][0];
            // rank-ordered RMW passes; singleton groups -> exactly 1 pass
            for (int pass = 0; __any(rank >= pass); ++pass) {
                if (rank == pass) {
                    float4 a = *pp;
                    a.x += v0; a.y += v1; a.z += v2; a.w += v3;
                    *pp = a;
                }
            }
        }
    }
    __syncthreads();

    // ---- reduce 4 planes + MLP + pool; 4 node-batches of 256 ----
    const float eps = eps_p[0];
    for (int half = 0; half < 4; ++half) {
        int node = t + half * ACCTH;           // 0..1023
        float4 a = *(const float4*)&planes[0][node][0];
#pragma unroll
        for (int w = 1; w < ACCW; ++w) {
            float4 bq = *(const float4*)&planes[w][node][0];
            a.x += bq.x; a.y += bq.y; a.z += bq.z; a.w += bq.w;
        }

        int n = bin * BIN_SIZE + node;         // one node per thread
        bool valid = n < N;
        float o0 = 0.f, o1 = 0.f, o2 = 0.f, o3 = 0.f;
        int g = -1;
        if (valid) {
            float4 xv = x[n];
            float h0 = (1.0f + eps) * xv.x + a.x;
            float h1 = (1.0f + eps) * xv.y + a.y;
            float h2 = (1.0f + eps) * xv.z + a.z;
            float h3 = (1.0f + eps) * xv.w + a.w;

            float tmp[16];
#pragma unroll
            for (int j = 0; j < 16; ++j) {
                float v = b1[j] + h0 * W1[j] + h1 * W1[16 + j] + h2 * W1[32 + j] + h3 * W1[48 + j];
                tmp[j] = v > 0.0f ? v : 0.0f;
            }
            float o[4];
#pragma unroll
            for (int j = 0; j < 4; ++j) {
                float v = b2[j];
#pragma unroll
                for (int k = 0; k < 16; ++k) v += tmp[k] * W2[k * 4 + j];
                o[j] = v > 0.0f ? v : 0.0f;
            }
            o0 = o[0]; o1 = o[1]; o2 = o[2]; o3 = o[3];
            g = batch[n];
        }

        // batch is sorted -> waves almost always graph-uniform
        int g0 = __shfl(g, 0);
        bool uni = __all(g == g0);
        if (uni && g0 >= 0) {
#pragma unroll
            for (int off = 32; off > 0; off >>= 1) {
                o0 += __shfl_down(o0, off);
                o1 += __shfl_down(o1, off);
                o2 += __shfl_down(o2, off);
                o3 += __shfl_down(o3, off);
            }
            if (lane == 0) {
                unsafeAtomicAdd(&gsum[(size_t)g0 * 4 + 0], o0);
                unsafeAtomicAdd(&gsum[(size_t)g0 * 4 + 1], o1);
                unsafeAtomicAdd(&gsum[(size_t)g0 * 4 + 2], o2);
                unsafeAtomicAdd(&gsum[(size_t)g0 * 4 + 3], o3);
                unsafeAtomicAdd(&gcnt[g0], 64.0f);
            }
        } else if (valid) {
            unsafeAtomicAdd(&gsum[(size_t)g * 4 + 0], o0);
            unsafeAtomicAdd(&gsum[(size_t)g * 4 + 1], o1);
            unsafeAtomicAdd(&gsum[(size_t)g * 4 + 2], o2);
            unsafeAtomicAdd(&gsum[(size_t)g * 4 + 3], o3);
            unsafeAtomicAdd(&gcnt[g], 1.0f);
        }
    }
}

// ---------------------------------------------------------------------------
// pooled = sums / max(cnt,1); out = log_softmax per graph.
// ---------------------------------------------------------------------------
__global__ void pool_softmax_kernel(const float* __restrict__ gsum,
                                    const float* __restrict__ gcnt,
                                    float* __restrict__ out) {
    int g = blockIdx.x * blockDim.x + threadIdx.x;
    if (g >= NUM_GRAPHS) return;
    float c = fmaxf(gcnt[g], 1.0f);
    float p0 = gsum[g * 4 + 0] / c;
    float p1 = gsum[g * 4 + 1] / c;
    float p2 = gsum[g * 4 + 2] / c;
    float p3 = gsum[g * 4 + 3] / c;
    float m = fmaxf(fmaxf(p0, p1), fmaxf(p2, p3));
    float s = expf(p0 - m) + expf(p1 - m) + expf(p2 - m) + expf(p3 - m);
    float lse = m + logf(s);
    out[g * 4 + 0] = p0 - lse;
    out[g * 4 + 1] = p1 - lse;
    out[g * 4 + 2] = p2 - lse;
    out[g * 4 + 3] = p3 - lse;
}

// ---------------------------------------------------------------------------
// Fallback kernels (ws too small): direct atomic scatter + separate MLP/pool.
// ---------------------------------------------------------------------------
__global__ void edge_scatter_kernel(const float4* __restrict__ x,
                                    const int* __restrict__ src,
                                    const int* __restrict__ dst,
                                    float* __restrict__ agg,
                                    int E) {
    int t = blockIdx.x * blockDim.x + threadIdx.x;
    int e = t * 4;
    if (e + 3 < E) {
        int4 s = *(const int4*)(src + e);
        int4 d = *(const int4*)(dst + e);
        float4 xv;
        xv = x[s.x];
        unsafeAtomicAdd(&agg[(size_t)d.x * 4 + 0], xv.x);
        unsafeAtomicAdd(&agg[(size_t)d.x * 4 + 1], xv.y);
        unsafeAtomicAdd(&agg[(size_t)d.x * 4 + 2], xv.z);
        unsafeAtomicAdd(&agg[(size_t)d.x * 4 + 3], xv.w);
        xv = x[s.y];
        unsafeAtomicAdd(&agg[(size_t)d.y * 4 + 0], xv.x);
        unsafeAtomicAdd(&agg[(size_t)d.y * 4 + 1], xv.y);
        unsafeAtomicAdd(&agg[(size_t)d.y * 4 + 2], xv.z);
        unsafeAtomicAdd(&agg[(size_t)d.y * 4 + 3], xv.w);
        xv = x[s.z];
        unsafeAtomicAdd(&agg[(size_t)d.z * 4 + 0], xv.x);
        unsafeAtomicAdd(&agg[(size_t)d.z * 4 + 1], xv.y);
        unsafeAtomicAdd(&agg[(size_t)d.z * 4 + 2], xv.z);
        unsafeAtomicAdd(&agg[(size_t)d.z * 4 + 3], xv.w);
        xv = x[s.w];
        unsafeAtomicAdd(&agg[(size_t)d.w * 4 + 0], xv.x);
        unsafeAtomicAdd(&agg[(size_t)d.w * 4 + 1], xv.y);
        unsafeAtomicAdd(&agg[(size_t)d.w * 4 + 2], xv.z);
        unsafeAtomicAdd(&agg[(size_t)d.w * 4 + 3], xv.w);
    } else {
        for (int i = e; i < E; ++i) {
            int sv = src[i], dv = dst[i];
            float4 xv = x[sv];
            unsafeAtomicAdd(&agg[(size_t)dv * 4 + 0], xv.x);
            unsafeAtomicAdd(&agg[(size_t)dv * 4 + 1], xv.y);
            unsafeAtomicAdd(&agg[(size_t)dv * 4 + 2], xv.z);
            unsafeAtomicAdd(&agg[(size_t)dv * 4 + 3], xv.w);
        }
    }
}

__global__ void node_mlp_pool_kernel(const float4* __restrict__ x,
                                     const float4* __restrict__ agg,
                                     const int* __restrict__ batch,
                                     const float* __restrict__ eps_p,
                                     const float* __restrict__ W1,
                                     const float* __restrict__ b1,
                                     const float* __restrict__ W2,
                                     const float* __restrict__ b2,
                                     float* __restrict__ gsum,
                                     float* __restrict__ gcnt,
                                     int N) {
    int i = blockIdx.x * blockDim.x + threadIdx.x;
    bool valid = i < N;
    float o0 = 0.f, o1 = 0.f, o2 = 0.f, o3 = 0.f;
    int g = -1;
    if (valid) {
        float eps = eps_p[0];
        float4 xv = x[i];
        float4 av = agg[i];
        float h0 = (1.0f + eps) * xv.x + av.x;
        float h1 = (1.0f + eps) * xv.y + av.y;
        float h2 = (1.0f + eps) * xv.z + av.z;
        float h3 = (1.0f + eps) * xv.w + av.w;
        float tmp[16];
#pragma unroll
        for (int j = 0; j < 16; ++j) {
            float v = b1[j] + h0 * W1[j] + h1 * W1[16 + j] + h2 * W1[32 + j] + h3 * W1[48 + j];
            tmp[j] = v > 0.0f ? v : 0.0f;
        }
        float o[4];
#pragma unroll
        for (int j = 0; j < 4; ++j) {
            float v = b2[j];
#pragma unroll
            for (int k = 0; k < 16; ++k) v += tmp[k] * W2[k * 4 + j];
            o[j] = v > 0.0f ? v : 0.0f;
        }
        o0 = o[0]; o1 = o[1]; o2 = o[2]; o3 = o[3];
        g = batch[i];
    }
    int g0 = __shfl(g, 0);
    bool uni = __all(g == g0);
    if (uni && g0 >= 0) {
#pragma unroll
        for (int off = 32; off > 0; off >>= 1) {
            o0 += __shfl_down(o0, off);
            o1 += __shfl_down(o1, off);
            o2 += __shfl_down(o2, off);
            o3 += __shfl_down(o3, off);
        }
        if ((threadIdx.x & 63) == 0) {
            unsafeAtomicAdd(&gsum[(size_t)g0 * 4 + 0], o0);
            unsafeAtomicAdd(&gsum[(size_t)g0 * 4 + 1], o1);
            unsafeAtomicAdd(&gsum[(size_t)g0 * 4 + 2], o2);
            unsafeAtomicAdd(&gsum[(size_t)g0 * 4 + 3], o3);
            unsafeAtomicAdd(&gcnt[g0], 64.0f);
        }
    } else if (valid) {
        unsafeAtomicAdd(&gsum[(size_t)g * 4 + 0], o0);
        unsafeAtomicAdd(&gsum[(size_t)g * 4 + 1], o1);
        unsafeAtomicAdd(&gsum[(size_t)g * 4 + 2], o2);
        unsafeAtomicAdd(&gsum[(size_t)g * 4 + 3], o3);
        unsafeAtomicAdd(&gcnt[g], 1.0f);
    }
}

extern "C" void kernel_launch(void* const* d_in, const int* in_sizes, int n_in,
                              void* d_out, int out_size, void* d_ws, size_t ws_size,
                              hipStream_t stream) {
    const float* x     = (const float*)d_in[0];
    const int*   ei    = (const int*)d_in[1];
    const int*   batch = (const int*)d_in[2];
    const float* eps   = (const float*)d_in[3];
    const float* W1    = (const float*)d_in[4];
    const float* b1    = (const float*)d_in[5];
    const float* W2    = (const float*)d_in[6];
    const float* b2    = (const float*)d_in[7];

    const int N = in_sizes[0] / 4;
    const int E = in_sizes[1] / 2;
    const int* src = ei;
    const int* dst = ei + (size_t)E;

    const int nb = (N + BIN_SIZE - 1) >> BIN_BITS;   // 489 for N=500K
    const int epb = (E + nb - 1) / nb;
    int cap = epb + epb / 8 + 1024;                  // ~28 sigma headroom
    cap = (cap + 3) & ~3;                            // 16B-align chunk bases

    // Fast-path ws layout: x16 [2N] | packed [nb*cap] | cursor [512*CURS] |
    //                      gsum [G*4] | gcnt [G]      (4 B units)
    size_t x16_elems = ((size_t)2 * N + 3) & ~(size_t)3;
    size_t packed_elems = ((size_t)nb * cap + 3) & ~(size_t)3;
    size_t need = (x16_elems + packed_elems + 512 * CURS + NUM_GRAPHS * 5) * sizeof(float);

    if (nb <= 512 && N < (1 << 19) && need <= ws_size) {
        uint2* x16    = (uint2*)d_ws;
        int*   packed = (int*)d_ws + x16_elems;
        int*   cursor = packed + packed_elems;
        float* gsum   = (float*)(cursor + 512 * CURS);
        float* gcnt   = gsum + (size_t)NUM_GRAPHS * 4;

        prep_kernel<<<(N + 511) / 512, 512, 0, stream>>>(
            (const float4*)x, x16, N, cursor, gsum, gcnt, cap);

        int nblocks_e = (E + EB - 1) / EB;
        bin_scatter<<<nblocks_e, STH, 0, stream>>>(src, dst, packed, cursor, E, cap, nb);

        bin_accum_mlp_pool<<<nb, ACCTH, 0, stream>>>(
            (const float4*)x, (const uint2*)x16, packed, cursor, batch, eps,
            W1, b1, W2, b2, gsum, gcnt, N, cap);

        pool_softmax_kernel<<<(NUM_GRAPHS + 255) / 256, 256, 0, stream>>>(
            gsum, gcnt, (float*)d_out);
    } else {
        float* agg  = (float*)d_ws;
        float* gsum = agg + (size_t)N * 4;
        float* gcnt = gsum + (size_t)NUM_GRAPHS * 4;
        size_t zero_bytes = ((size_t)N * 4 + NUM_GRAPHS * 5) * sizeof(float);
        (void)hipMemsetAsync(d_ws, 0, zero_bytes, stream);

        int e4 = (E + 3) / 4;
        edge_scatter_kernel<<<(e4 + 255) / 256, 256, 0, stream>>>(
            (const float4*)x, src, dst, agg, E);

        node_mlp_pool_kernel<<<(N + 255) / 256, 256, 0, stream>>>(
            (const float4*)x, (const float4*)agg, batch, eps, W1, b1, W2, b2,
            gsum, gcnt, N);

        pool_softmax_kernel<<<(NUM_GRAPHS + 255) / 256, 256, 0, stream>>>(
            gsum, gcnt, (float*)d_out);
    }
}